// Round 2
// baseline (447.533 us; speedup 1.0000x reference)
//
#include <hip/hip_runtime.h>
#include <hip/hip_bf16.h>

// Problem: B=4, T=2048, C=1024, H=16, D=64.
// Buffers may be f32 or bf16 (harness ambiguity) -> device-side dtype probe.
// ws layout (shorts):
//   [0..63]    flag (int at offset 0): 1 = buffers are f32, 0 = bf16
//   XB_OFF  : canonical bf16 x [4][2048][1024]           (8388608 shorts)
//   WT_OFF  : bf16 Wt[3][16][64][1024] (transposed W)    (3145728 shorts)
//   QKV_OFF : bf16 qkv[3][4][16][2048][64]               (25165824 shorts)

typedef __attribute__((ext_vector_type(8))) short short8;  // 8 bf16
typedef __attribute__((ext_vector_type(4))) float f32x4;

#define XB_OFF  64
#define WT_OFF  (64 + 8388608)
#define QKV_OFF (64 + 8388608 + 3145728)

__device__ __forceinline__ short f2bf(float f) {
    union { float f; unsigned u; } un; un.f = f;
    unsigned r = un.u + 0x7fffu + ((un.u >> 16) & 1u);   // RNE
    return (short)(r >> 16);
}

// ---------------- kernel P: dtype probe ----------------
__global__ __launch_bounds__(256) void detect_dtype(const unsigned short* __restrict__ xs,
                                                    int* __restrict__ flag) {
    __shared__ int red[256];
    int t = threadIdx.x, cnt = 0;
    for (int i = t; i < 8192; i += 256) {
        unsigned e = (xs[i] >> 7) & 0xFFu;   // bf16 exponent field
        if (e >= 0xC0u) cnt++;               // |v| >= 2^65: impossible for real data
    }
    red[t] = cnt;
    __syncthreads();
    for (int s = 128; s > 0; s >>= 1) { if (t < s) red[t] += red[t + s]; __syncthreads(); }
    if (t == 0) flag[0] = (red[0] > 16) ? 1 : 0;
}

// ---------------- kernel C: x -> canonical bf16 ----------------
__global__ __launch_bounds__(256) void convert_x(const void* __restrict__ xin,
                                                 const int* __restrict__ flag,
                                                 short* __restrict__ xb) {
    const bool isf = (flag[0] != 0);
    const int n8 = 8388608 / 8;
    int i = blockIdx.x * 256 + threadIdx.x;
    const int stride = gridDim.x * 256;
    for (; i < n8; i += stride) {
        short8 v;
        if (isf) {
            const f32x4* xf = (const f32x4*)xin + i * 2;
            f32x4 a = xf[0], b = xf[1];
#pragma unroll
            for (int j = 0; j < 4; ++j) { v[j] = f2bf(a[j]); v[4 + j] = f2bf(b[j]); }
        } else {
            v = ((const short8*)xin)[i];
        }
        ((short8*)xb)[i] = v;
    }
}

// ---------------- kernel 0: W [16][1024][64] -> Wt [16][64][1024] (bf16) ----------------
__global__ __launch_bounds__(256) void transpose_w(const void* __restrict__ W0,
                                                   const void* __restrict__ W1,
                                                   const void* __restrict__ W2,
                                                   const int* __restrict__ flag,
                                                   short* __restrict__ Wt) {
    __shared__ short tile[64][72];
    const bool isf = (flag[0] != 0);
    const int s  = blockIdx.z;
    const void* W = (s == 0) ? W0 : (s == 1) ? W1 : W2;
    const int h  = blockIdx.y;
    const int c0 = blockIdx.x * 64;
    const int t  = threadIdx.x;
#pragma unroll
    for (int p = 0; p < 2; ++p) {
        int f8 = t + p * 256;           // 0..511
        int r  = f8 >> 3;               // c-offset 0..63
        int c8 = (f8 & 7) * 8;          // d-offset
        size_t base = (size_t)(h * 1024 + c0 + r) * 64 + c8;
        short8 v;
        if (isf) {
            const float* wf = (const float*)W + base;
#pragma unroll
            for (int j = 0; j < 8; ++j) v[j] = f2bf(wf[j]);
        } else {
            v = *(const short8*)((const short*)W + base);
        }
        *(short8*)&tile[r][c8] = v;
    }
    __syncthreads();
#pragma unroll
    for (int p = 0; p < 2; ++p) {
        int f8 = t + p * 256;
        int d  = f8 >> 3;               // 0..63
        int c8 = (f8 & 7) * 8;          // c-offset within tile
        short8 v;
#pragma unroll
        for (int j = 0; j < 8; ++j) v[j] = tile[c8 + j][d];
        *(short8*)(Wt + (size_t)((s * 16 + h) * 64 + d) * 1024 + c0 + c8) = v;
    }
}

// ---------------- kernel 1: QKV projection ----------------
// grid: (32, 16, 12), block 256 (4 waves). Each block: 64x64 output tile, K=1024.
__global__ __launch_bounds__(256) void qkv_gemm(const short* __restrict__ xb,   // [4][2048][1024]
                                                const short* __restrict__ Wt,   // [3][16][64][1024]
                                                short* __restrict__ qkv) {      // [3][4][16][2048][64]
    __shared__ short As[64][40];
    __shared__ short Bs[64][40];
    const int m0 = blockIdx.x * 64;
    const int h  = blockIdx.y;
    const int b  = blockIdx.z & 3;
    const int s  = blockIdx.z >> 2;
    const int tid = threadIdx.x;
    const int w  = tid >> 6, l = tid & 63;
    const int lr = l & 15, lg = l >> 4;

    f32x4 acc[4] = {};
    const short* xrow = xb + (size_t)(b * 2048 + m0) * 1024;
    const short* wrow = Wt + (size_t)((s * 16 + h) * 64) * 1024;

    const int ar = tid >> 2, ac = (tid & 3) * 8;   // 256 thr x 8 elems = 64x32
    for (int k0 = 0; k0 < 1024; k0 += 32) {
        *(short8*)&As[ar][ac] = *(const short8*)(xrow + (size_t)ar * 1024 + k0 + ac);
        *(short8*)&Bs[ar][ac] = *(const short8*)(wrow + (size_t)ar * 1024 + k0 + ac);
        __syncthreads();
        short8 a = *(const short8*)&As[w * 16 + lr][lg * 8];
#pragma unroll
        for (int nt = 0; nt < 4; ++nt) {
            short8 bf = *(const short8*)&Bs[nt * 16 + lr][lg * 8];
            acc[nt] = __builtin_amdgcn_mfma_f32_16x16x32_bf16(a, bf, acc[nt], 0, 0, 0);
        }
        __syncthreads();
    }
    short* orow = qkv + (size_t)((s * 4 + b) * 16 + h) * 2048 * 64;
#pragma unroll
    for (int nt = 0; nt < 4; ++nt)
#pragma unroll
        for (int r = 0; r < 4; ++r) {
            int row = m0 + w * 16 + lg * 4 + r;   // D: row=(l>>4)*4+reg, col=l&15
            int col = nt * 16 + lr;
            orow[(size_t)row * 64 + col] = f2bf(acc[nt][r]);
        }
}

// ---------------- kernel 2: causal flash attention ----------------
// grid: (32, 16, 4), block 256 (4 waves x 16 q-rows). KVBLK=64.
__global__ __launch_bounds__(256) void attn(const short* __restrict__ qkv,
                                            const int* __restrict__ flag,
                                            void* __restrict__ outp) {
    __shared__ short Ks[64][72];
    __shared__ short Vt[64][72];
    __shared__ short Ps[4][16][72];
    const bool isf = (flag[0] != 0);
    const int qb = (int)gridDim.x - 1 - (int)blockIdx.x;  // heavy blocks first
    const int q0 = qb * 64;
    const int h  = blockIdx.y;
    const int b  = blockIdx.z;
    const int tid = threadIdx.x;
    const int w  = tid >> 6, l = tid & 63;
    const int lr = l & 15, lg = l >> 4;
    const size_t BHTD = (size_t)4 * 16 * 2048 * 64;
    const short* Qb = qkv + (size_t)(b * 16 + h) * 2048 * 64;
    const short* Kb = Qb + BHTD;
    const short* Vb = Qb + 2 * BHTD;

    short8 aq[2];
#pragma unroll
    for (int sd = 0; sd < 2; ++sd)
        aq[sd] = *(const short8*)(Qb + (size_t)(q0 + w * 16 + lr) * 64 + sd * 32 + lg * 8);

    float mr[4], lsum[4];
    f32x4 o[4] = {};
#pragma unroll
    for (int r = 0; r < 4; ++r) { mr[r] = -3.0e38f; lsum[r] = 0.f; }

    const int ntiles = qb + 1;
    for (int kt = 0; kt < ntiles; ++kt) {
        const int kv0 = kt * 64;
#pragma unroll
        for (int p = 0; p < 2; ++p) {
            int f8 = tid + p * 256;
            int r  = f8 >> 3, c8 = (f8 & 7) * 8;
            *(short8*)&Ks[r][c8] = *(const short8*)(Kb + (size_t)(kv0 + r) * 64 + c8);
            short8 v = *(const short8*)(Vb + (size_t)(kv0 + r) * 64 + c8);
#pragma unroll
            for (int j = 0; j < 8; ++j) Vt[c8 + j][r] = v[j];
        }
        __syncthreads();

        f32x4 sf[4];
#pragma unroll
        for (int nt = 0; nt < 4; ++nt) {
            f32x4 z = {};
            short8 kb0 = *(const short8*)&Ks[nt * 16 + lr][lg * 8];
            short8 kb1 = *(const short8*)&Ks[nt * 16 + lr][32 + lg * 8];
            z = __builtin_amdgcn_mfma_f32_16x16x32_bf16(aq[0], kb0, z, 0, 0, 0);
            z = __builtin_amdgcn_mfma_f32_16x16x32_bf16(aq[1], kb1, z, 0, 0, 0);
            sf[nt] = z;
        }
        const int qrow = q0 + w * 16 + lg * 4;   // + r
#pragma unroll
        for (int r = 0; r < 4; ++r) {
            float mx = -3.0e38f;
#pragma unroll
            for (int nt = 0; nt < 4; ++nt) {
                float sv = sf[nt][r] * 0.125f;
                int kg = kv0 + nt * 16 + lr;
                sv = (kg <= qrow + r) ? sv : -3.0e38f;
                sf[nt][r] = sv;
                mx = fmaxf(mx, sv);
            }
#pragma unroll
            for (int d = 1; d < 16; d <<= 1) mx = fmaxf(mx, __shfl_xor(mx, d));
            float mnew  = fmaxf(mr[r], mx);
            float alpha = __expf(mr[r] - mnew);
            float rs = 0.f;
#pragma unroll
            for (int nt = 0; nt < 4; ++nt) {
                float pv = __expf(sf[nt][r] - mnew);
                sf[nt][r] = pv;
                rs += pv;
            }
#pragma unroll
            for (int d = 1; d < 16; d <<= 1) rs += __shfl_xor(rs, d);
            lsum[r] = lsum[r] * alpha + rs;
            mr[r]   = mnew;
#pragma unroll
            for (int nt = 0; nt < 4; ++nt) o[nt][r] *= alpha;
        }
#pragma unroll
        for (int nt = 0; nt < 4; ++nt)
#pragma unroll
            for (int r = 0; r < 4; ++r)
                Ps[w][lg * 4 + r][nt * 16 + lr] = f2bf(sf[nt][r]);
#pragma unroll
        for (int ks = 0; ks < 2; ++ks) {
            short8 pa = *(const short8*)&Ps[w][lr][ks * 32 + lg * 8];
#pragma unroll
            for (int nt = 0; nt < 4; ++nt) {
                short8 vb = *(const short8*)&Vt[nt * 16 + lr][ks * 32 + lg * 8];
                o[nt] = __builtin_amdgcn_mfma_f32_16x16x32_bf16(pa, vb, o[nt], 0, 0, 0);
            }
        }
        __syncthreads();
    }
#pragma unroll
    for (int nt = 0; nt < 4; ++nt)
#pragma unroll
        for (int r = 0; r < 4; ++r) {
            int t = q0 + w * 16 + lg * 4 + r;
            int d = nt * 16 + lr;
            size_t idx = (size_t)(b * 2048 + t) * 1024 + h * 64 + d;
            float val = o[nt][r] / lsum[r];
            if (isf) ((float*)outp)[idx] = val;
            else     ((short*)outp)[idx] = f2bf(val);
        }
}

extern "C" void kernel_launch(void* const* d_in, const int* in_sizes, int n_in,
                              void* d_out, int out_size, void* d_ws, size_t ws_size,
                              hipStream_t stream) {
    short* ws   = (short*)d_ws;
    int*  flag  = (int*)d_ws;
    short* xb   = ws + XB_OFF;
    short* Wt   = ws + WT_OFF;
    short* qkvb = ws + QKV_OFF;

    dim3 blk(256);
    detect_dtype<<<1, blk, 0, stream>>>((const unsigned short*)d_in[0], flag);
    convert_x<<<dim3(1024), blk, 0, stream>>>(d_in[0], flag, xb);
    transpose_w<<<dim3(16, 16, 3), blk, 0, stream>>>(d_in[1], d_in[2], d_in[3], flag, Wt);
    qkv_gemm<<<dim3(32, 16, 12), blk, 0, stream>>>(xb, Wt, qkvb);
    attn<<<dim3(32, 16, 4), blk, 0, stream>>>(qkvb, flag, d_out);
}

// Round 3
// 370.134 us; speedup vs baseline: 1.2091x; 1.2091x over previous
//
#include <hip/hip_runtime.h>
#include <hip/hip_bf16.h>

// Problem: B=4, T=2048, C=1024, H=16, D=64.
// Buffers may be f32 or bf16 (harness ambiguity) -> device-side dtype probe.
// ws layout (shorts):
//   [0..63]    flag (int at offset 0): 1 = buffers are f32, 0 = bf16
//   XB_OFF  : canonical bf16 x [4][2048][1024]           (8388608 shorts)
//   WT_OFF  : bf16 Wt[3][16][64][1024] (transposed W)    (3145728 shorts)
//   QKV_OFF : bf16 qkv[3][4][16][2048][64]               (25165824 shorts)

typedef __attribute__((ext_vector_type(8))) short short8;  // 8 bf16
typedef __attribute__((ext_vector_type(4))) float f32x4;

#define XB_OFF  64
#define WT_OFF  (64 + 8388608)
#define QKV_OFF (64 + 8388608 + 3145728)

__device__ __forceinline__ short f2bf(float f) {
    union { float f; unsigned u; } un; un.f = f;
    unsigned r = un.u + 0x7fffu + ((un.u >> 16) & 1u);   // RNE
    return (short)(r >> 16);
}

// XOR-swizzled byte offset into a [rows][72-short] LDS tile (data in first
// 128B of each 144B row). Bijective per row; same fn for read and write.
// Spreads bank-quads: writes conflict-free, b128 reads at 8-cycle floor.
__device__ __forceinline__ int swz(int row, int colByte) {
    return row * 144 + (colByte ^ ((row & 56) << 1));   // ((row>>3)&7)<<4
}

// ---------------- kernel P: dtype probe ----------------
__global__ __launch_bounds__(256) void detect_dtype(const unsigned short* __restrict__ xs,
                                                    int* __restrict__ flag) {
    __shared__ int red[256];
    int t = threadIdx.x, cnt = 0;
    for (int i = t; i < 8192; i += 256) {
        unsigned e = (xs[i] >> 7) & 0xFFu;   // bf16 exponent field
        if (e >= 0xC0u) cnt++;               // |v| >= 2^65: impossible for real data
    }
    red[t] = cnt;
    __syncthreads();
    for (int s = 128; s > 0; s >>= 1) { if (t < s) red[t] += red[t + s]; __syncthreads(); }
    if (t == 0) flag[0] = (red[0] > 16) ? 1 : 0;
}

// ---------------- kernel C: x -> canonical bf16 ----------------
__global__ __launch_bounds__(256) void convert_x(const void* __restrict__ xin,
                                                 const int* __restrict__ flag,
                                                 short* __restrict__ xb) {
    const bool isf = (flag[0] != 0);
    const int n8 = 8388608 / 8;
    int i = blockIdx.x * 256 + threadIdx.x;
    const int stride = gridDim.x * 256;
    for (; i < n8; i += stride) {
        short8 v;
        if (isf) {
            const f32x4* xf = (const f32x4*)xin + i * 2;
            f32x4 a = xf[0], b = xf[1];
#pragma unroll
            for (int j = 0; j < 4; ++j) { v[j] = f2bf(a[j]); v[4 + j] = f2bf(b[j]); }
        } else {
            v = ((const short8*)xin)[i];
        }
        ((short8*)xb)[i] = v;
    }
}

// ---------------- kernel 0: W [16][1024][64] -> Wt [16][64][1024] (bf16) ----------------
__global__ __launch_bounds__(256) void transpose_w(const void* __restrict__ W0,
                                                   const void* __restrict__ W1,
                                                   const void* __restrict__ W2,
                                                   const int* __restrict__ flag,
                                                   short* __restrict__ Wt) {
    __shared__ short tile[64][72];
    const bool isf = (flag[0] != 0);
    const int s  = blockIdx.z;
    const void* W = (s == 0) ? W0 : (s == 1) ? W1 : W2;
    const int h  = blockIdx.y;
    const int c0 = blockIdx.x * 64;
    const int t  = threadIdx.x;
#pragma unroll
    for (int p = 0; p < 2; ++p) {
        int f8 = t + p * 256;           // 0..511
        int r  = f8 >> 3;               // c-offset 0..63
        int c8 = (f8 & 7) * 8;          // d-offset
        size_t base = (size_t)(h * 1024 + c0 + r) * 64 + c8;
        short8 v;
        if (isf) {
            const float* wf = (const float*)W + base;
#pragma unroll
            for (int j = 0; j < 8; ++j) v[j] = f2bf(wf[j]);
        } else {
            v = *(const short8*)((const short*)W + base);
        }
        *(short8*)&tile[r][c8] = v;
    }
    __syncthreads();
#pragma unroll
    for (int p = 0; p < 2; ++p) {
        int f8 = t + p * 256;
        int d  = f8 >> 3;               // 0..63
        int c8 = (f8 & 7) * 8;          // c-offset within tile
        short8 v;
#pragma unroll
        for (int j = 0; j < 8; ++j) v[j] = tile[c8 + j][d];
        *(short8*)(Wt + (size_t)((s * 16 + h) * 64 + d) * 1024 + c0 + c8) = v;
    }
}

// ---------------- kernel 1: QKV projection ----------------
// grid: (32, 16, 12), block 256 (4 waves). Each block: 64x64 output tile, K=1024.
__global__ __launch_bounds__(256) void qkv_gemm(const short* __restrict__ xb,   // [4][2048][1024]
                                                const short* __restrict__ Wt,   // [3][16][64][1024]
                                                short* __restrict__ qkv) {      // [3][4][16][2048][64]
    __shared__ short As[64][40];
    __shared__ short Bs[64][40];
    const int m0 = blockIdx.x * 64;
    const int h  = blockIdx.y;
    const int b  = blockIdx.z & 3;
    const int s  = blockIdx.z >> 2;
    const int tid = threadIdx.x;
    const int w  = tid >> 6, l = tid & 63;
    const int lr = l & 15, lg = l >> 4;

    f32x4 acc[4] = {};
    const short* xrow = xb + (size_t)(b * 2048 + m0) * 1024;
    const short* wrow = Wt + (size_t)((s * 16 + h) * 64) * 1024;

    const int ar = tid >> 2, ac = (tid & 3) * 8;   // 256 thr x 8 elems = 64x32
    for (int k0 = 0; k0 < 1024; k0 += 32) {
        *(short8*)&As[ar][ac] = *(const short8*)(xrow + (size_t)ar * 1024 + k0 + ac);
        *(short8*)&Bs[ar][ac] = *(const short8*)(wrow + (size_t)ar * 1024 + k0 + ac);
        __syncthreads();
        short8 a = *(const short8*)&As[w * 16 + lr][lg * 8];
#pragma unroll
        for (int nt = 0; nt < 4; ++nt) {
            short8 bf = *(const short8*)&Bs[nt * 16 + lr][lg * 8];
            acc[nt] = __builtin_amdgcn_mfma_f32_16x16x32_bf16(a, bf, acc[nt], 0, 0, 0);
        }
        __syncthreads();
    }
    short* orow = qkv + (size_t)((s * 4 + b) * 16 + h) * 2048 * 64;
#pragma unroll
    for (int nt = 0; nt < 4; ++nt)
#pragma unroll
        for (int r = 0; r < 4; ++r) {
            int row = m0 + w * 16 + lg * 4 + r;   // D: row=(l>>4)*4+reg, col=l&15
            int col = nt * 16 + lr;
            orow[(size_t)row * 64 + col] = f2bf(acc[nt][r]);
        }
}

// ---------------- kernel 2: causal flash attention ----------------
// grid: (16, 16, 4), block 256 (4 waves); QBLK=128 (32 q-rows/wave), KVBLK=64.
// All LDS tiles XOR-swizzled. K/V staged global->regs early, LDS-write late.
__global__ __launch_bounds__(256) void attn(const short* __restrict__ qkv,
                                            const int* __restrict__ flag,
                                            void* __restrict__ outp) {
    __shared__ short Ks_l[64 * 72];
    __shared__ short Vt_l[64 * 72];        // logical [d][key], swizzled
    __shared__ short Ps_l[4 * 32 * 72];    // per-wave 32 q-rows x 64 keys
    char* const KsB = (char*)Ks_l;
    char* const VtB = (char*)Vt_l;
    char* const PsB = (char*)Ps_l;

    const bool isf = (flag[0] != 0);
    const int qb = (int)gridDim.x - 1 - (int)blockIdx.x;  // heavy blocks first
    const int q0 = qb * 128;
    const int h  = blockIdx.y;
    const int b  = blockIdx.z;
    const int tid = threadIdx.x;
    const int w  = tid >> 6, l = tid & 63;
    const int lr = l & 15, lg = l >> 4;
    const size_t BHTD = (size_t)4 * 16 * 2048 * 64;
    const short* Qb = qkv + (size_t)(b * 16 + h) * 2048 * 64;
    const short* Kb = Qb + BHTD;
    const short* Vb = Qb + 2 * BHTD;

    // staging coords (per thread): 2 chunks of (row r, 8 cols at c8)
    const int sr0 = tid >> 3, sc8 = (tid & 7) * 8;   // rows 0..31 / cols
    short8 kreg[2], vreg[2];

    // Q fragments: wave w owns q rows q0 + w*32 + rg*16 + lr
    short8 aq[2][2];
#pragma unroll
    for (int rg = 0; rg < 2; ++rg)
#pragma unroll
        for (int sd = 0; sd < 2; ++sd)
            aq[rg][sd] = *(const short8*)(Qb + (size_t)(q0 + w * 32 + rg * 16 + lr) * 64 + sd * 32 + lg * 8);

    float mr[2][4], lsum[2][4];
    f32x4 o[2][4] = {};
#pragma unroll
    for (int rg = 0; rg < 2; ++rg)
#pragma unroll
        for (int r = 0; r < 4; ++r) { mr[rg][r] = -3.0e38f; lsum[rg][r] = 0.f; }

    const int ntiles = 2 * qb + 2;

    // prologue: stage tile 0
#pragma unroll
    for (int p = 0; p < 2; ++p) {
        int r = sr0 + p * 32;
        kreg[p] = *(const short8*)(Kb + (size_t)r * 64 + sc8);
        vreg[p] = *(const short8*)(Vb + (size_t)r * 64 + sc8);
    }
#pragma unroll
    for (int p = 0; p < 2; ++p) {
        int r = sr0 + p * 32;
        *(short8*)(KsB + swz(r, sc8 * 2)) = kreg[p];
#pragma unroll
        for (int j = 0; j < 8; ++j)
            *(short*)(VtB + swz(sc8 + j, r * 2)) = vreg[p][j];
    }
    __syncthreads();

    for (int kt = 0; kt < ntiles; ++kt) {
        const int kv0 = kt * 64;
        // issue next tile's global loads early (hide HBM under compute)
        if (kt + 1 < ntiles) {
            const size_t nb = (size_t)(kv0 + 64) * 64;
#pragma unroll
            for (int p = 0; p < 2; ++p) {
                int r = sr0 + p * 32;
                kreg[p] = *(const short8*)(Kb + nb + (size_t)r * 64 + sc8);
                vreg[p] = *(const short8*)(Vb + nb + (size_t)r * 64 + sc8);
            }
        }

        // S = Q K^T (both row-groups share K fragments)
        f32x4 sf[2][4];
#pragma unroll
        for (int nt = 0; nt < 4; ++nt) {
            short8 kb0 = *(const short8*)(KsB + swz(nt * 16 + lr, lg * 16));
            short8 kb1 = *(const short8*)(KsB + swz(nt * 16 + lr, 64 + lg * 16));
#pragma unroll
            for (int rg = 0; rg < 2; ++rg) {
                f32x4 z = {};
                z = __builtin_amdgcn_mfma_f32_16x16x32_bf16(aq[rg][0], kb0, z, 0, 0, 0);
                z = __builtin_amdgcn_mfma_f32_16x16x32_bf16(aq[rg][1], kb1, z, 0, 0, 0);
                sf[rg][nt] = z;
            }
        }

        // online softmax per row-group, per accumulator row
#pragma unroll
        for (int rg = 0; rg < 2; ++rg) {
            const int qrow = q0 + w * 32 + rg * 16 + lg * 4;   // + r
#pragma unroll
            for (int r = 0; r < 4; ++r) {
                float mx = -3.0e38f;
#pragma unroll
                for (int nt = 0; nt < 4; ++nt) {
                    float sv = sf[rg][nt][r] * 0.125f;
                    int kg = kv0 + nt * 16 + lr;
                    sv = (kg <= qrow + r) ? sv : -3.0e38f;
                    sf[rg][nt][r] = sv;
                    mx = fmaxf(mx, sv);
                }
#pragma unroll
                for (int d = 1; d < 16; d <<= 1) mx = fmaxf(mx, __shfl_xor(mx, d));
                float mnew  = fmaxf(mr[rg][r], mx);
                float alpha = __expf(mr[rg][r] - mnew);
                float rs = 0.f;
#pragma unroll
                for (int nt = 0; nt < 4; ++nt) {
                    float pv = __expf(sf[rg][nt][r] - mnew);
                    sf[rg][nt][r] = pv;
                    rs += pv;
                }
#pragma unroll
                for (int d = 1; d < 16; d <<= 1) rs += __shfl_xor(rs, d);
                lsum[rg][r] = lsum[rg][r] * alpha + rs;
                mr[rg][r]   = mnew;
#pragma unroll
                for (int nt = 0; nt < 4; ++nt) o[rg][nt][r] *= alpha;
            }
            // P -> LDS (per-wave region, swizzled scalar writes ~conflict-free)
#pragma unroll
            for (int nt = 0; nt < 4; ++nt)
#pragma unroll
                for (int r = 0; r < 4; ++r)
                    *(short*)(PsB + swz(w * 32 + rg * 16 + lg * 4 + r, (nt * 16 + lr) * 2)) =
                        f2bf(sf[rg][nt][r]);
        }

        // O += P V
#pragma unroll
        for (int ks = 0; ks < 2; ++ks) {
            short8 pa[2];
#pragma unroll
            for (int rg = 0; rg < 2; ++rg)
                pa[rg] = *(const short8*)(PsB + swz(w * 32 + rg * 16 + lr, ks * 64 + lg * 16));
#pragma unroll
            for (int nt = 0; nt < 4; ++nt) {
                short8 vb = *(const short8*)(VtB + swz(nt * 16 + lr, ks * 64 + lg * 16));
#pragma unroll
                for (int rg = 0; rg < 2; ++rg)
                    o[rg][nt] = __builtin_amdgcn_mfma_f32_16x16x32_bf16(pa[rg], vb, o[rg][nt], 0, 0, 0);
            }
        }

        __syncthreads();   // all waves done reading K/V tile kt
        if (kt + 1 < ntiles) {
#pragma unroll
            for (int p = 0; p < 2; ++p) {
                int r = sr0 + p * 32;
                *(short8*)(KsB + swz(r, sc8 * 2)) = kreg[p];
#pragma unroll
                for (int j = 0; j < 8; ++j)
                    *(short*)(VtB + swz(sc8 + j, r * 2)) = vreg[p][j];
            }
            __syncthreads();
        }
    }

    // epilogue: normalize, write [B][T][H*D]
#pragma unroll
    for (int rg = 0; rg < 2; ++rg)
#pragma unroll
        for (int nt = 0; nt < 4; ++nt)
#pragma unroll
            for (int r = 0; r < 4; ++r) {
                int t = q0 + w * 32 + rg * 16 + lg * 4 + r;
                int d = nt * 16 + lr;
                size_t idx = (size_t)(b * 2048 + t) * 1024 + h * 64 + d;
                float val = o[rg][nt][r] / lsum[rg][r];
                if (isf) ((float*)outp)[idx] = val;
                else     ((short*)outp)[idx] = f2bf(val);
            }
}

extern "C" void kernel_launch(void* const* d_in, const int* in_sizes, int n_in,
                              void* d_out, int out_size, void* d_ws, size_t ws_size,
                              hipStream_t stream) {
    short* ws   = (short*)d_ws;
    int*  flag  = (int*)d_ws;
    short* xb   = ws + XB_OFF;
    short* Wt   = ws + WT_OFF;
    short* qkvb = ws + QKV_OFF;

    dim3 blk(256);
    detect_dtype<<<1, blk, 0, stream>>>((const unsigned short*)d_in[0], flag);
    convert_x<<<dim3(1024), blk, 0, stream>>>(d_in[0], flag, xb);
    transpose_w<<<dim3(16, 16, 3), blk, 0, stream>>>(d_in[1], d_in[2], d_in[3], flag, Wt);
    qkv_gemm<<<dim3(32, 16, 12), blk, 0, stream>>>(xb, Wt, qkvb);
    attn<<<dim3(16, 16, 4), blk, 0, stream>>>(qkvb, flag, d_out);
}

// Round 4
// 297.765 us; speedup vs baseline: 1.5030x; 1.2430x over previous
//
#include <hip/hip_runtime.h>
#include <hip/hip_bf16.h>

// Problem: B=4, T=2048, C=1024, H=16, D=64.
// Buffers may be f32 or bf16 (harness ambiguity) -> device-side dtype probe.
// ws layout (shorts):
//   [0..63]    flag (int at offset 0): 1 = buffers are f32, 0 = bf16
//   XB_OFF  : canonical bf16 x [4][2048][1024]           (8388608 shorts)
//   WT_OFF  : bf16 Wt[3][16][64][1024] (transposed W)    (3145728 shorts)
//   QKV_OFF : bf16 qkv[3][4][16][2048][64]               (25165824 shorts)
// Q is pre-scaled by 0.125*log2(e) in qkv_gemm; attn softmax runs in exp2 domain.

typedef __attribute__((ext_vector_type(8))) short short8;   // 8 bf16
typedef __attribute__((ext_vector_type(4))) float f32x4;
typedef __attribute__((ext_vector_type(16))) float f32x16;

#define XB_OFF  64
#define WT_OFF  (64 + 8388608)
#define QKV_OFF (64 + 8388608 + 3145728)

__device__ __forceinline__ short f2bf(float f) {
    union { float f; unsigned u; } un; un.f = f;
    unsigned r = un.u + 0x7fffu + ((un.u >> 16) & 1u);   // RNE
    return (short)(r >> 16);
}
__device__ __forceinline__ float bf2f(short v) {
    union { unsigned u; float f; } un; un.u = ((unsigned)(unsigned short)v) << 16;
    return un.f;
}
__device__ __forceinline__ unsigned cvtpk_bf16(float lo, float hi) {
    unsigned r;
    asm("v_cvt_pk_bf16_f32 %0, %1, %2" : "=v"(r) : "v"(lo), "v"(hi));
    return r;
}

// XOR-swizzled byte offset into a [rows][72-short] LDS tile (data in first
// 128B of each 144B row). Bijective per row; same fn for read and write.
__device__ __forceinline__ int swz(int row, int colByte) {
    return row * 144 + (colByte ^ ((row & 56) << 1));   // ((row>>3)&7)<<4
}

// ---------------- kernel P: dtype probe ----------------
__global__ __launch_bounds__(256) void detect_dtype(const unsigned short* __restrict__ xs,
                                                    int* __restrict__ flag) {
    __shared__ int red[256];
    int t = threadIdx.x, cnt = 0;
    for (int i = t; i < 8192; i += 256) {
        unsigned e = (xs[i] >> 7) & 0xFFu;
        if (e >= 0xC0u) cnt++;               // |v| >= 2^65: impossible for real data
    }
    red[t] = cnt;
    __syncthreads();
    for (int s = 128; s > 0; s >>= 1) { if (t < s) red[t] += red[t + s]; __syncthreads(); }
    if (t == 0) flag[0] = (red[0] > 16) ? 1 : 0;
}

// ---------------- kernel C: x -> canonical bf16 ----------------
__global__ __launch_bounds__(256) void convert_x(const void* __restrict__ xin,
                                                 const int* __restrict__ flag,
                                                 short* __restrict__ xb) {
    const bool isf = (flag[0] != 0);
    const int n8 = 8388608 / 8;
    int i = blockIdx.x * 256 + threadIdx.x;
    const int stride = gridDim.x * 256;
    for (; i < n8; i += stride) {
        short8 v;
        if (isf) {
            const f32x4* xf = (const f32x4*)xin + i * 2;
            f32x4 a = xf[0], b = xf[1];
#pragma unroll
            for (int j = 0; j < 4; ++j) { v[j] = f2bf(a[j]); v[4 + j] = f2bf(b[j]); }
        } else {
            v = ((const short8*)xin)[i];
        }
        ((short8*)xb)[i] = v;
    }
}

// ---------------- kernel 0: W [16][1024][64] -> Wt [16][64][1024] (bf16) ----------------
__global__ __launch_bounds__(256) void transpose_w(const void* __restrict__ W0,
                                                   const void* __restrict__ W1,
                                                   const void* __restrict__ W2,
                                                   const int* __restrict__ flag,
                                                   short* __restrict__ Wt) {
    __shared__ short tile[64][72];
    const bool isf = (flag[0] != 0);
    const int s  = blockIdx.z;
    const void* W = (s == 0) ? W0 : (s == 1) ? W1 : W2;
    const int h  = blockIdx.y;
    const int c0 = blockIdx.x * 64;
    const int t  = threadIdx.x;
#pragma unroll
    for (int p = 0; p < 2; ++p) {
        int f8 = t + p * 256;
        int r  = f8 >> 3;
        int c8 = (f8 & 7) * 8;
        size_t base = (size_t)(h * 1024 + c0 + r) * 64 + c8;
        short8 v;
        if (isf) {
            const float* wf = (const float*)W + base;
#pragma unroll
            for (int j = 0; j < 8; ++j) v[j] = f2bf(wf[j]);
        } else {
            v = *(const short8*)((const short*)W + base);
        }
        *(short8*)&tile[r][c8] = v;
    }
    __syncthreads();
#pragma unroll
    for (int p = 0; p < 2; ++p) {
        int f8 = t + p * 256;
        int d  = f8 >> 3;
        int c8 = (f8 & 7) * 8;
        short8 v;
#pragma unroll
        for (int j = 0; j < 8; ++j) v[j] = tile[c8 + j][d];
        *(short8*)(Wt + (size_t)((s * 16 + h) * 64 + d) * 1024 + c0 + c8) = v;
    }
}

// ---------------- kernel 1: QKV projection (Q pre-scaled) ----------------
__global__ __launch_bounds__(256) void qkv_gemm(const short* __restrict__ xb,
                                                const short* __restrict__ Wt,
                                                short* __restrict__ qkv) {
    __shared__ short As[64][40];
    __shared__ short Bs[64][40];
    const int m0 = blockIdx.x * 64;
    const int h  = blockIdx.y;
    const int b  = blockIdx.z & 3;
    const int s  = blockIdx.z >> 2;
    const int tid = threadIdx.x;
    const int w  = tid >> 6, l = tid & 63;
    const int lr = l & 15, lg = l >> 4;

    f32x4 acc[4] = {};
    const short* xrow = xb + (size_t)(b * 2048 + m0) * 1024;
    const short* wrow = Wt + (size_t)((s * 16 + h) * 64) * 1024;

    const int ar = tid >> 2, ac = (tid & 3) * 8;
    for (int k0 = 0; k0 < 1024; k0 += 32) {
        *(short8*)&As[ar][ac] = *(const short8*)(xrow + (size_t)ar * 1024 + k0 + ac);
        *(short8*)&Bs[ar][ac] = *(const short8*)(wrow + (size_t)ar * 1024 + k0 + ac);
        __syncthreads();
        short8 a = *(const short8*)&As[w * 16 + lr][lg * 8];
#pragma unroll
        for (int nt = 0; nt < 4; ++nt) {
            short8 bf = *(const short8*)&Bs[nt * 16 + lr][lg * 8];
            acc[nt] = __builtin_amdgcn_mfma_f32_16x16x32_bf16(a, bf, acc[nt], 0, 0, 0);
        }
        __syncthreads();
    }
    const float qs = (s == 0) ? 0.18033688f : 1.0f;   // 0.125 * log2(e)
    short* orow = qkv + (size_t)((s * 4 + b) * 16 + h) * 2048 * 64;
#pragma unroll
    for (int nt = 0; nt < 4; ++nt)
#pragma unroll
        for (int r = 0; r < 4; ++r) {
            int row = m0 + w * 16 + lg * 4 + r;
            int col = nt * 16 + lr;
            orow[(size_t)row * 64 + col] = f2bf(acc[nt][r] * qs);
        }
}

// ---------------- kernel 2: causal flash attention (swapped 32x32 MFMA) ----------------
// grid: (16, 16, 4), block 256 (4 waves x 32 queries each). KVBLK=64.
// S^T = K·Q^T per 32-key group -> lane owns one query column -> in-register softmax.
// PV computed as O^T = V^T · P^T so rescale stays lane-local.
#define BUILD_PW(s, stx, base) {                                             \
    unsigned P01 = cvtpk_bf16(stx[base + 0], stx[base + 1]);                 \
    unsigned P23 = cvtpk_bf16(stx[base + 2], stx[base + 3]);                 \
    unsigned P45 = cvtpk_bf16(stx[base + 4], stx[base + 5]);                 \
    unsigned P67 = cvtpk_bf16(stx[base + 6], stx[base + 7]);                 \
    unsigned Q01 = (unsigned)__shfl_xor((int)P01, 32);                       \
    unsigned Q23 = (unsigned)__shfl_xor((int)P23, 32);                       \
    unsigned Q45 = (unsigned)__shfl_xor((int)P45, 32);                       \
    unsigned Q67 = (unsigned)__shfl_xor((int)P67, 32);                       \
    pw[s][0] = hl ? Q45 : P01;  pw[s][1] = hl ? Q67 : P23;                   \
    pw[s][2] = hl ? P45 : Q01;  pw[s][3] = hl ? P67 : Q23;                   \
}

__global__ __launch_bounds__(256) void attn(const short* __restrict__ qkv,
                                            const int* __restrict__ flag,
                                            void* __restrict__ outp) {
    __shared__ short lds_all[9216];            // Ks[64][72] + Vt[64][72]; reused as Ot[128][72]
    char* const KsB = (char*)lds_all;
    char* const VtB = (char*)(lds_all + 4608);
    const bool isf = (flag[0] != 0);
    const int qb = (int)gridDim.x - 1 - (int)blockIdx.x;  // heavy blocks first
    const int q0 = qb * 128;
    const int h  = blockIdx.y;
    const int b  = blockIdx.z;
    const int tid = threadIdx.x;
    const int w  = tid >> 6, l = tid & 63;
    const int q_ = l & 31;        // query col within wave tile / key row within group
    const int hl = l >> 5;        // lane half
    const size_t BHTD = (size_t)4 * 16 * 2048 * 64;
    const short* Qb = qkv + (size_t)(b * 16 + h) * 2048 * 64;
    const short* Kb = Qb + BHTD;
    const short* Vb = Qb + 2 * BHTD;

    const int qg = q0 + w * 32 + q_;           // this lane's global query row

    // Q^T fragments (B-operand): lane needs Q[qg][s*16 + hl*8 + j]
    short8 aq[4];
#pragma unroll
    for (int s = 0; s < 4; ++s)
        aq[s] = *(const short8*)(Qb + (size_t)qg * 64 + s * 16 + hl * 8);

    float mr = -1.0e30f, lsum = 0.f;
    f32x16 o0 = {}, o1 = {};                   // O^T: d rows 0-31 / 32-63

    const int sr0 = tid >> 3, sc8 = (tid & 7) * 8;
    short8 kreg[2], vreg[2];
#pragma unroll
    for (int p = 0; p < 2; ++p) {
        int r = sr0 + p * 32;
        kreg[p] = *(const short8*)(Kb + (size_t)r * 64 + sc8);
        vreg[p] = *(const short8*)(Vb + (size_t)r * 64 + sc8);
    }
#pragma unroll
    for (int p = 0; p < 2; ++p) {
        int r = sr0 + p * 32;
        *(short8*)(KsB + swz(r, sc8 * 2)) = kreg[p];
#pragma unroll
        for (int j = 0; j < 8; ++j)
            *(short*)(VtB + swz(sc8 + j, r * 2)) = vreg[p][j];
    }
    __syncthreads();

    const int ntiles = 2 * qb + 2;
    for (int kt = 0; kt < ntiles; ++kt) {
        if (kt + 1 < ntiles) {                 // issue next tile's loads early
            const short* Kn = Kb + (size_t)(kt + 1) * 64 * 64;
            const short* Vn = Vb + (size_t)(kt + 1) * 64 * 64;
#pragma unroll
            for (int p = 0; p < 2; ++p) {
                int r = sr0 + p * 32;
                kreg[p] = *(const short8*)(Kn + (size_t)r * 64 + sc8);
                vreg[p] = *(const short8*)(Vn + (size_t)r * 64 + sc8);
            }
        }

        // S^T = K Q^T  (two 32-key groups)
        f32x16 st0 = {}, st1 = {};
#pragma unroll
        for (int s = 0; s < 4; ++s) {
            short8 kf0 = *(const short8*)(KsB + swz(q_,      s * 32 + hl * 16));
            short8 kf1 = *(const short8*)(KsB + swz(32 + q_, s * 32 + hl * 16));
            st0 = __builtin_amdgcn_mfma_f32_32x32x16_bf16(kf0, aq[s], st0, 0, 0, 0);
            st1 = __builtin_amdgcn_mfma_f32_32x32x16_bf16(kf1, aq[s], st1, 0, 0, 0);
        }
        const int kv0 = kt * 64;
        if (kt >= ntiles - 2) {                // only last 2 tiles touch the diagonal
#pragma unroll
            for (int r = 0; r < 16; ++r) {
                int key = kv0 + (r & 3) + 8 * (r >> 2) + 4 * hl;
                st0[r] = (key      <= qg) ? st0[r] : -1.0e30f;
                st1[r] = (key + 32 <= qg) ? st1[r] : -1.0e30f;
            }
        }
        // in-register online softmax (exp2 domain; Q pre-scaled)
        float mx = fmaxf(st0[0], st1[0]);
#pragma unroll
        for (int r = 1; r < 16; ++r) mx = fmaxf(mx, fmaxf(st0[r], st1[r]));
        mx = fmaxf(mx, __shfl_xor(mx, 32));
        float mnew  = fmaxf(mr, mx);
        float alpha = exp2f(mr - mnew);
        mr = mnew;
        float rs = 0.f;
#pragma unroll
        for (int r = 0; r < 16; ++r) {
            st0[r] = exp2f(st0[r] - mnew); rs += st0[r];
            st1[r] = exp2f(st1[r] - mnew); rs += st1[r];
        }
        rs += __shfl_xor(rs, 32);
        lsum = lsum * alpha + rs;
#pragma unroll
        for (int r = 0; r < 16; ++r) { o0[r] *= alpha; o1[r] *= alpha; }

        // P^T fragments in-register (cvt_pk + half-exchange)
        unsigned pw[4][4];
        BUILD_PW(0, st0, 0)
        BUILD_PW(1, st0, 8)
        BUILD_PW(2, st1, 0)
        BUILD_PW(3, st1, 8)

        // O^T += V^T P^T
#pragma unroll
        for (int s = 0; s < 4; ++s) {
            union { unsigned u[4]; short8 s8; } pb;
            pb.u[0] = pw[s][0]; pb.u[1] = pw[s][1]; pb.u[2] = pw[s][2]; pb.u[3] = pw[s][3];
            short8 v0 = *(const short8*)(VtB + swz(q_,      s * 32 + hl * 16));
            short8 v1 = *(const short8*)(VtB + swz(32 + q_, s * 32 + hl * 16));
            o0 = __builtin_amdgcn_mfma_f32_32x32x16_bf16(v0, pb.s8, o0, 0, 0, 0);
            o1 = __builtin_amdgcn_mfma_f32_32x32x16_bf16(v1, pb.s8, o1, 0, 0, 0);
        }

        __syncthreads();
        if (kt + 1 < ntiles) {
#pragma unroll
            for (int p = 0; p < 2; ++p) {
                int r = sr0 + p * 32;
                *(short8*)(KsB + swz(r, sc8 * 2)) = kreg[p];
#pragma unroll
                for (int j = 0; j < 8; ++j)
                    *(short*)(VtB + swz(sc8 + j, r * 2)) = vreg[p][j];
            }
            __syncthreads();
        }
    }

    // epilogue: O^T -> LDS [q][d] -> coalesced global stores
    const float inv = 1.0f / lsum;
    char* const OtB = (char*)lds_all;          // [128][72] shorts
    const int qlocal = w * 32 + q_;
#pragma unroll
    for (int r = 0; r < 16; ++r) {
        int d0 = (r & 3) + 8 * (r >> 2) + 4 * hl;
        *(short*)(OtB + swz(qlocal, 2 * d0))        = f2bf(o0[r] * inv);
        *(short*)(OtB + swz(qlocal, 2 * (32 + d0))) = f2bf(o1[r] * inv);
    }
    __syncthreads();
#pragma unroll
    for (int i = 0; i < 4; ++i) {
        int idx = i * 256 + tid;               // 0..1023
        int row = idx >> 3, c8 = (idx & 7) * 8;
        short8 vch = *(const short8*)(OtB + swz(row, c8 * 2));
        size_t obase = (size_t)(b * 2048 + q0 + row) * 1024 + h * 64 + c8;
        if (isf) {
            f32x4 lo, hi;
#pragma unroll
            for (int j = 0; j < 4; ++j) { lo[j] = bf2f(vch[j]); hi[j] = bf2f(vch[4 + j]); }
            *(f32x4*)((float*)outp + obase)     = lo;
            *(f32x4*)((float*)outp + obase + 4) = hi;
        } else {
            *(short8*)((short*)outp + obase) = vch;
        }
    }
}

extern "C" void kernel_launch(void* const* d_in, const int* in_sizes, int n_in,
                              void* d_out, int out_size, void* d_ws, size_t ws_size,
                              hipStream_t stream) {
    short* ws   = (short*)d_ws;
    int*  flag  = (int*)d_ws;
    short* xb   = ws + XB_OFF;
    short* Wt   = ws + WT_OFF;
    short* qkvb = ws + QKV_OFF;

    dim3 blk(256);
    detect_dtype<<<1, blk, 0, stream>>>((const unsigned short*)d_in[0], flag);
    convert_x<<<dim3(1024), blk, 0, stream>>>(d_in[0], flag, xb);
    transpose_w<<<dim3(16, 16, 3), blk, 0, stream>>>(d_in[1], d_in[2], d_in[3], flag, Wt);
    qkv_gemm<<<dim3(32, 16, 12), blk, 0, stream>>>(xb, Wt, qkvb);
    attn<<<dim3(16, 16, 4), blk, 0, stream>>>(qkvb, flag, d_out);
}

// Round 5
// 222.792 us; speedup vs baseline: 2.0087x; 1.3365x over previous
//
#include <hip/hip_runtime.h>
#include <hip/hip_bf16.h>

// Problem: B=4, T=2048, C=1024, H=16, D=64.
// Buffers may be f32 or bf16 (harness ambiguity) -> device-side dtype probe.
// ws layout (shorts):
//   [0..63]    flag (int at offset 0): 1 = buffers are f32, 0 = bf16
//   XB_OFF  : canonical bf16 x [4][2048][1024]           (8388608 shorts)
//   WT_OFF  : bf16 Wt[3][16][64][1024] (transposed W)    (3145728 shorts)
//   QKV_OFF : bf16 qkv[3][4][16][2048][64]               (25165824 shorts)
// Q is pre-scaled by 0.125*log2(e); attn softmax runs in exp2 domain.

typedef __attribute__((ext_vector_type(8))) short short8;   // 8 bf16
typedef __attribute__((ext_vector_type(4))) float f32x4;
typedef __attribute__((ext_vector_type(16))) float f32x16;

#define XB_OFF  64
#define WT_OFF  (64 + 8388608)
#define QKV_OFF (64 + 8388608 + 3145728)

__device__ __forceinline__ short f2bf(float f) {
    union { float f; unsigned u; } un; un.f = f;
    unsigned r = un.u + 0x7fffu + ((un.u >> 16) & 1u);   // RNE
    return (short)(r >> 16);
}
__device__ __forceinline__ float bf2f(short v) {
    union { unsigned u; float f; } un; un.u = ((unsigned)(unsigned short)v) << 16;
    return un.f;
}
__device__ __forceinline__ unsigned cvtpk_bf16(float lo, float hi) {
    unsigned r;
    asm("v_cvt_pk_bf16_f32 %0, %1, %2" : "=v"(r) : "v"(lo), "v"(hi));
    return r;
}

// XOR-swizzled byte offset into a [rows][72-short] LDS tile (data in first
// 128B of each 144B row). Bijective per row; same fn for read and write.
__device__ __forceinline__ int swz(int row, int colByte) {
    return row * 144 + (colByte ^ ((row & 56) << 1));   // ((row>>3)&7)<<4
}

// ---------------- kernel P: dtype probe ----------------
__global__ __launch_bounds__(256) void detect_dtype(const unsigned short* __restrict__ xs,
                                                    int* __restrict__ flag) {
    __shared__ int red[256];
    int t = threadIdx.x, cnt = 0;
    for (int i = t; i < 8192; i += 256) {
        unsigned e = (xs[i] >> 7) & 0xFFu;
        if (e >= 0xC0u) cnt++;               // |v| >= 2^65: impossible for real data
    }
    red[t] = cnt;
    __syncthreads();
    for (int s = 128; s > 0; s >>= 1) { if (t < s) red[t] += red[t + s]; __syncthreads(); }
    if (t == 0) flag[0] = (red[0] > 16) ? 1 : 0;
}

// ---------------- kernel C: x -> canonical bf16 ----------------
__global__ __launch_bounds__(256) void convert_x(const void* __restrict__ xin,
                                                 const int* __restrict__ flag,
                                                 short* __restrict__ xb) {
    const bool isf = (flag[0] != 0);
    const int n8 = 8388608 / 8;
    int i = blockIdx.x * 256 + threadIdx.x;
    const int stride = gridDim.x * 256;
    for (; i < n8; i += stride) {
        short8 v;
        if (isf) {
            const f32x4* xf = (const f32x4*)xin + i * 2;
            f32x4 a = xf[0], b = xf[1];
#pragma unroll
            for (int j = 0; j < 4; ++j) { v[j] = f2bf(a[j]); v[4 + j] = f2bf(b[j]); }
        } else {
            v = ((const short8*)xin)[i];
        }
        ((short8*)xb)[i] = v;
    }
}

// ---------------- kernel 0: W [16][1024][64] -> Wt [16][64][1024] (bf16) ----------------
__global__ __launch_bounds__(256) void transpose_w(const void* __restrict__ W0,
                                                   const void* __restrict__ W1,
                                                   const void* __restrict__ W2,
                                                   const int* __restrict__ flag,
                                                   short* __restrict__ Wt) {
    __shared__ short tile[64][72];
    const bool isf = (flag[0] != 0);
    const int s  = blockIdx.z;
    const void* W = (s == 0) ? W0 : (s == 1) ? W1 : W2;
    const int h  = blockIdx.y;
    const int c0 = blockIdx.x * 64;
    const int t  = threadIdx.x;
#pragma unroll
    for (int p = 0; p < 2; ++p) {
        int f8 = t + p * 256;
        int r  = f8 >> 3;
        int c8 = (f8 & 7) * 8;
        size_t base = (size_t)(h * 1024 + c0 + r) * 64 + c8;
        short8 v;
        if (isf) {
            const float* wf = (const float*)W + base;
#pragma unroll
            for (int j = 0; j < 8; ++j) v[j] = f2bf(wf[j]);
        } else {
            v = *(const short8*)((const short*)W + base);
        }
        *(short8*)&tile[r][c8] = v;
    }
    __syncthreads();
#pragma unroll
    for (int p = 0; p < 2; ++p) {
        int f8 = t + p * 256;
        int d  = f8 >> 3;
        int c8 = (f8 & 7) * 8;
        short8 v;
#pragma unroll
        for (int j = 0; j < 8; ++j) v[j] = tile[c8 + j][d];
        *(short8*)(Wt + (size_t)((s * 16 + h) * 64 + d) * 1024 + c0 + c8) = v;
    }
}

// ---------------- kernel 1: QKV projection (Q pre-scaled) ----------------
__global__ __launch_bounds__(256) void qkv_gemm(const short* __restrict__ xb,
                                                const short* __restrict__ Wt,
                                                short* __restrict__ qkv) {
    __shared__ short As[64][40];
    __shared__ short Bs[64][40];
    const int m0 = blockIdx.x * 64;
    const int h  = blockIdx.y;
    const int b  = blockIdx.z & 3;
    const int s  = blockIdx.z >> 2;
    const int tid = threadIdx.x;
    const int w  = tid >> 6, l = tid & 63;
    const int lr = l & 15, lg = l >> 4;

    f32x4 acc[4] = {};
    const short* xrow = xb + (size_t)(b * 2048 + m0) * 1024;
    const short* wrow = Wt + (size_t)((s * 16 + h) * 64) * 1024;

    const int ar = tid >> 2, ac = (tid & 3) * 8;
    for (int k0 = 0; k0 < 1024; k0 += 32) {
        *(short8*)&As[ar][ac] = *(const short8*)(xrow + (size_t)ar * 1024 + k0 + ac);
        *(short8*)&Bs[ar][ac] = *(const short8*)(wrow + (size_t)ar * 1024 + k0 + ac);
        __syncthreads();
        short8 a = *(const short8*)&As[w * 16 + lr][lg * 8];
#pragma unroll
        for (int nt = 0; nt < 4; ++nt) {
            short8 bf = *(const short8*)&Bs[nt * 16 + lr][lg * 8];
            acc[nt] = __builtin_amdgcn_mfma_f32_16x16x32_bf16(a, bf, acc[nt], 0, 0, 0);
        }
        __syncthreads();
    }
    const float qs = (s == 0) ? 0.18033688f : 1.0f;   // 0.125 * log2(e)
    short* orow = qkv + (size_t)((s * 4 + b) * 16 + h) * 2048 * 64;
#pragma unroll
    for (int nt = 0; nt < 4; ++nt)
#pragma unroll
        for (int r = 0; r < 4; ++r) {
            int row = m0 + w * 16 + lg * 4 + r;
            int col = nt * 16 + lr;
            orow[(size_t)row * 64 + col] = f2bf(acc[nt][r] * qs);
        }
}

// ---------------- kernel 2: balanced causal flash attention ----------------
// grid (8,16,4): block qbl handles q-tiles {qbl, 15-qbl} (equal work: 34
// subtile-computes each). One KV sweep serves both (light range is a prefix
// of heavy). Double-buffered LDS (1 barrier/tile). Swapped 32x32 MFMA with
// in-register softmax, defer-max, lane-local lsum.
#define BUILD_PW(s, stx, base) {                                             \
    unsigned P01 = cvtpk_bf16(stx[base + 0], stx[base + 1]);                 \
    unsigned P23 = cvtpk_bf16(stx[base + 2], stx[base + 3]);                 \
    unsigned P45 = cvtpk_bf16(stx[base + 4], stx[base + 5]);                 \
    unsigned P67 = cvtpk_bf16(stx[base + 6], stx[base + 7]);                 \
    unsigned Q01 = (unsigned)__shfl_xor((int)P01, 32);                       \
    unsigned Q23 = (unsigned)__shfl_xor((int)P23, 32);                       \
    unsigned Q45 = (unsigned)__shfl_xor((int)P45, 32);                       \
    unsigned Q67 = (unsigned)__shfl_xor((int)P67, 32);                       \
    pw[s][0] = hl ? Q45 : P01;  pw[s][1] = hl ? Q67 : P23;                   \
    pw[s][2] = hl ? P45 : Q01;  pw[s][3] = hl ? P67 : Q23;                   \
}

__device__ __forceinline__ void process_tile(const char* KsB, const char* VtB,
                                             short8 a0, short8 a1, short8 a2, short8 a3,
                                             float& mr, float& ls,
                                             f32x16& o0, f32x16& o1,
                                             int qg, int kv0, bool diag,
                                             int q_, int hl) {
    short8 aq[4] = {a0, a1, a2, a3};
    f32x16 st0 = {}, st1 = {};
#pragma unroll
    for (int s = 0; s < 4; ++s) {
        short8 kf0 = *(const short8*)(KsB + swz(q_,      s * 32 + hl * 16));
        short8 kf1 = *(const short8*)(KsB + swz(32 + q_, s * 32 + hl * 16));
        st0 = __builtin_amdgcn_mfma_f32_32x32x16_bf16(kf0, aq[s], st0, 0, 0, 0);
        st1 = __builtin_amdgcn_mfma_f32_32x32x16_bf16(kf1, aq[s], st1, 0, 0, 0);
    }
    if (diag) {
#pragma unroll
        for (int r = 0; r < 16; ++r) {
            int key = kv0 + (r & 3) + 8 * (r >> 2) + 4 * hl;
            st0[r] = (key      <= qg) ? st0[r] : -1.0e30f;
            st1[r] = (key + 32 <= qg) ? st1[r] : -1.0e30f;
        }
    }
    float mx = fmaxf(st0[0], st1[0]);
#pragma unroll
    for (int r = 1; r < 16; ++r) mx = fmaxf(mx, fmaxf(st0[r], st1[r]));
    mx = fmaxf(mx, __shfl_xor(mx, 32));
    if (!__all(mx <= mr + 8.0f)) {        // defer-max: skip rescale on small growth
        float mnew  = fmaxf(mr, mx);
        float alpha = exp2f(mr - mnew);
        ls *= alpha;
#pragma unroll
        for (int r = 0; r < 16; ++r) { o0[r] *= alpha; o1[r] *= alpha; }
        mr = mnew;
    }
    float rs = 0.f;
#pragma unroll
    for (int r = 0; r < 16; ++r) {
        st0[r] = exp2f(st0[r] - mr); rs += st0[r];
        st1[r] = exp2f(st1[r] - mr); rs += st1[r];
    }
    ls += rs;                              // lane-local; partner half added at end
    unsigned pw[4][4];
    BUILD_PW(0, st0, 0)
    BUILD_PW(1, st0, 8)
    BUILD_PW(2, st1, 0)
    BUILD_PW(3, st1, 8)
#pragma unroll
    for (int s = 0; s < 4; ++s) {
        union { unsigned u[4]; short8 s8; } pb;
        pb.u[0] = pw[s][0]; pb.u[1] = pw[s][1]; pb.u[2] = pw[s][2]; pb.u[3] = pw[s][3];
        short8 v0 = *(const short8*)(VtB + swz(q_,      s * 32 + hl * 16));
        short8 v1 = *(const short8*)(VtB + swz(32 + q_, s * 32 + hl * 16));
        o0 = __builtin_amdgcn_mfma_f32_32x32x16_bf16(v0, pb.s8, o0, 0, 0, 0);
        o1 = __builtin_amdgcn_mfma_f32_32x32x16_bf16(v1, pb.s8, o1, 0, 0, 0);
    }
}

#define EPILOGUE(oA, oB, lsv, q0base) {                                           \
    __syncthreads();                                                              \
    float inv = 1.0f / (lsv);                                                     \
    const int qlocal = w * 32 + q_;                                               \
    _Pragma("unroll")                                                             \
    for (int r = 0; r < 16; r += 2) {                                             \
        int d0 = (r & 3) + 8 * (r >> 2) + 4 * hl;                                 \
        *(unsigned*)(OtB + swz(qlocal, 2 * d0)) =                                 \
            cvtpk_bf16(oA[r] * inv, oA[r + 1] * inv);                             \
        *(unsigned*)(OtB + swz(qlocal, 2 * (32 + d0))) =                          \
            cvtpk_bf16(oB[r] * inv, oB[r + 1] * inv);                             \
    }                                                                             \
    __syncthreads();                                                              \
    _Pragma("unroll")                                                             \
    for (int i2 = 0; i2 < 4; ++i2) {                                              \
        int idx = i2 * 256 + tid;                                                 \
        int row = idx >> 3, cc8 = (idx & 7) * 8;                                  \
        short8 vch = *(const short8*)(OtB + swz(row, cc8 * 2));                   \
        size_t obase = (size_t)(b * 2048 + (q0base) + row) * 1024 + h * 64 + cc8; \
        if (isf) {                                                                \
            f32x4 lo2, hi2;                                                       \
            _Pragma("unroll")                                                     \
            for (int j = 0; j < 4; ++j) { lo2[j] = bf2f(vch[j]); hi2[j] = bf2f(vch[4 + j]); } \
            *(f32x4*)((float*)outp + obase)     = lo2;                            \
            *(f32x4*)((float*)outp + obase + 4) = hi2;                            \
        } else {                                                                  \
            *(short8*)((short*)outp + obase) = vch;                               \
        }                                                                         \
    }                                                                             \
}

__global__ __launch_bounds__(256, 2) void attn(const short* __restrict__ qkv,
                                               const int* __restrict__ flag,
                                               void* __restrict__ outp) {
    __shared__ short lds_all[2 * 9216];    // dbuf {Ks[64*72], Vt[64*72]} = 36 KB
    const bool isf = (flag[0] != 0);
    const int h  = blockIdx.y;
    const int b  = blockIdx.z;
    const int tid = threadIdx.x;
    const int w  = tid >> 6, l = tid & 63;
    const int q_ = l & 31;
    const int hl = l >> 5;
    const size_t BHTD = (size_t)4 * 16 * 2048 * 64;
    const short* Qb = qkv + (size_t)(b * 16 + h) * 2048 * 64;
    const short* Kb = Qb + BHTD;
    const short* Vb = Qb + 2 * BHTD;

    const int qbs0 = blockIdx.x, qbs1 = 15 - qbs0;      // paired q-tiles
    const int nt0 = 2 * qbs0 + 2, nt1 = 2 * qbs1 + 2;   // nt0 <= nt1
    const int qg0 = qbs0 * 128 + w * 32 + q_;
    const int qg1 = qbs1 * 128 + w * 32 + q_;

    short8 aq0[4], aq1[4];
#pragma unroll
    for (int s = 0; s < 4; ++s) {
        aq0[s] = *(const short8*)(Qb + (size_t)qg0 * 64 + s * 16 + hl * 8);
        aq1[s] = *(const short8*)(Qb + (size_t)qg1 * 64 + s * 16 + hl * 8);
    }

    float mr0 = -1.0e30f, ls0 = 0.f, mr1 = -1.0e30f, ls1 = 0.f;
    f32x16 o00 = {}, o01 = {}, o10 = {}, o11 = {};

    // staging map: 2 adjacent key rows x 8 cols per thread
    const int kr = (tid >> 3) * 2;       // 0..62 even
    const int c8 = (tid & 7) * 8;
    short8 kreg[2], vreg[2];

    // prologue: stage tile 0 into buf 0
    {
        kreg[0] = *(const short8*)(Kb + (size_t)kr * 64 + c8);
        kreg[1] = *(const short8*)(Kb + (size_t)(kr + 1) * 64 + c8);
        vreg[0] = *(const short8*)(Vb + (size_t)kr * 64 + c8);
        vreg[1] = *(const short8*)(Vb + (size_t)(kr + 1) * 64 + c8);
        char* KsN = (char*)lds_all;
        char* VtN = KsN + 9216;
        *(short8*)(KsN + swz(kr,     c8 * 2)) = kreg[0];
        *(short8*)(KsN + swz(kr + 1, c8 * 2)) = kreg[1];
#pragma unroll
        for (int j = 0; j < 8; ++j) {
            unsigned pv = (unsigned)(unsigned short)vreg[0][j]
                        | ((unsigned)(unsigned short)vreg[1][j] << 16);
            *(unsigned*)(VtN + swz(c8 + j, kr * 2)) = pv;
        }
    }

    for (int kt = 0; kt < nt1; ++kt) {
        const char* KsB = (const char*)lds_all + (kt & 1) * 18432;
        const char* VtB = KsB + 9216;
        __syncthreads();                   // staged writes visible; prev readers done
        if (kt + 1 < nt1) {                // issue next tile's loads early
            const short* Kn = Kb + (size_t)(kt + 1) * 4096;
            const short* Vn = Vb + (size_t)(kt + 1) * 4096;
            kreg[0] = *(const short8*)(Kn + (size_t)kr * 64 + c8);
            kreg[1] = *(const short8*)(Kn + (size_t)(kr + 1) * 64 + c8);
            vreg[0] = *(const short8*)(Vn + (size_t)kr * 64 + c8);
            vreg[1] = *(const short8*)(Vn + (size_t)(kr + 1) * 64 + c8);
        }
        const int kv0 = kt * 64;
        process_tile(KsB, VtB, aq1[0], aq1[1], aq1[2], aq1[3], mr1, ls1,
                     o10, o11, qg1, kv0, kt >= 2 * qbs1, q_, hl);
        if (kt < nt0)
            process_tile(KsB, VtB, aq0[0], aq0[1], aq0[2], aq0[3], mr0, ls0,
                         o00, o01, qg0, kv0, kt >= 2 * qbs0, q_, hl);
        if (kt + 1 < nt1) {                // write next tile into other buffer
            char* KsN = (char*)lds_all + ((kt + 1) & 1) * 18432;
            char* VtN = KsN + 9216;
            *(short8*)(KsN + swz(kr,     c8 * 2)) = kreg[0];
            *(short8*)(KsN + swz(kr + 1, c8 * 2)) = kreg[1];
#pragma unroll
            for (int j = 0; j < 8; ++j) {
                unsigned pv = (unsigned)(unsigned short)vreg[0][j]
                            | ((unsigned)(unsigned short)vreg[1][j] << 16);
                *(unsigned*)(VtN + swz(c8 + j, kr * 2)) = pv;
            }
        }
    }

    ls0 += __shfl_xor(ls0, 32);
    ls1 += __shfl_xor(ls1, 32);
    char* const OtB = (char*)lds_all;      // epilogue reuses buffer 0 (128x72)
    EPILOGUE(o00, o01, ls0, qbs0 * 128)
    EPILOGUE(o10, o11, ls1, qbs1 * 128)
}

extern "C" void kernel_launch(void* const* d_in, const int* in_sizes, int n_in,
                              void* d_out, int out_size, void* d_ws, size_t ws_size,
                              hipStream_t stream) {
    short* ws   = (short*)d_ws;
    int*  flag  = (int*)d_ws;
    short* xb   = ws + XB_OFF;
    short* Wt   = ws + WT_OFF;
    short* qkvb = ws + QKV_OFF;

    dim3 blk(256);
    detect_dtype<<<1, blk, 0, stream>>>((const unsigned short*)d_in[0], flag);
    convert_x<<<dim3(1024), blk, 0, stream>>>(d_in[0], flag, xb);
    transpose_w<<<dim3(16, 16, 3), blk, 0, stream>>>(d_in[1], d_in[2], d_in[3], flag, Wt);
    qkv_gemm<<<dim3(32, 16, 12), blk, 0, stream>>>(xb, Wt, qkvb);
    attn<<<dim3(8, 16, 4), blk, 0, stream>>>(qkvb, flag, d_out);
}

// Round 6
// 170.242 us; speedup vs baseline: 2.6288x; 1.3087x over previous
//
#include <hip/hip_runtime.h>
#include <hip/hip_bf16.h>

// Problem: B=4, T=2048, C=1024, H=16, D=64.
// Buffers may be f32 or bf16 (harness ambiguity) -> device-side dtype probe.
// ws layout (shorts):
//   [0..63]    flag (int at offset 0): 1 = buffers are f32, 0 = bf16
//   XB_OFF  : canonical bf16 x [4][2048][1024]           (8388608 shorts)
//   WT_OFF  : bf16 Wt[3][16][64][1024] (transposed W)    (3145728 shorts)
//   QKV_OFF : bf16 qkv[3][4][16][2048][64]               (25165824 shorts)
// Q is pre-scaled by 0.125*log2(e); attn softmax runs in exp2 domain.

typedef __attribute__((ext_vector_type(8))) short short8;   // 8 bf16
typedef __attribute__((ext_vector_type(4))) float f32x4;
typedef __attribute__((ext_vector_type(16))) float f32x16;

#define XB_OFF  64
#define WT_OFF  (64 + 8388608)
#define QKV_OFF (64 + 8388608 + 3145728)

__device__ __forceinline__ short f2bf(float f) {
    union { float f; unsigned u; } un; un.f = f;
    unsigned r = un.u + 0x7fffu + ((un.u >> 16) & 1u);   // RNE
    return (short)(r >> 16);
}
__device__ __forceinline__ float bf2f(short v) {
    union { unsigned u; float f; } un; un.u = ((unsigned)(unsigned short)v) << 16;
    return un.f;
}
__device__ __forceinline__ unsigned cvtpk_bf16(float lo, float hi) {
    unsigned r;
    asm("v_cvt_pk_bf16_f32 %0, %1, %2" : "=v"(r) : "v"(lo), "v"(hi));
    return r;
}

// XOR-swizzled byte offset into a [rows][72-short] LDS tile (attn kernel).
__device__ __forceinline__ int swz(int row, int colByte) {
    return row * 144 + (colByte ^ ((row & 56) << 1));   // ((row>>3)&7)<<4
}

// async global->LDS, 16B per lane; LDS dest is wave-uniform base + lane*16
#define GLOAD16(gsrc, ldst)                                                       \
    __builtin_amdgcn_global_load_lds(                                             \
        (const __attribute__((address_space(1))) void*)(gsrc),                    \
        (__attribute__((address_space(3))) void*)(ldst), 16, 0, 0)

// ---------------- kernel P: dtype probe ----------------
__global__ __launch_bounds__(256) void detect_dtype(const unsigned short* __restrict__ xs,
                                                    int* __restrict__ flag) {
    __shared__ int red[256];
    int t = threadIdx.x, cnt = 0;
    for (int i = t; i < 8192; i += 256) {
        unsigned e = (xs[i] >> 7) & 0xFFu;
        if (e >= 0xC0u) cnt++;               // |v| >= 2^65: impossible for real data
    }
    red[t] = cnt;
    __syncthreads();
    for (int s = 128; s > 0; s >>= 1) { if (t < s) red[t] += red[t + s]; __syncthreads(); }
    if (t == 0) flag[0] = (red[0] > 16) ? 1 : 0;
}

// ---------------- kernel C: x -> canonical bf16 ----------------
__global__ __launch_bounds__(256) void convert_x(const void* __restrict__ xin,
                                                 const int* __restrict__ flag,
                                                 short* __restrict__ xb) {
    const bool isf = (flag[0] != 0);
    const int n8 = 8388608 / 8;
    int i = blockIdx.x * 256 + threadIdx.x;
    const int stride = gridDim.x * 256;
    for (; i < n8; i += stride) {
        short8 v;
        if (isf) {
            const f32x4* xf = (const f32x4*)xin + i * 2;
            f32x4 a = xf[0], b = xf[1];
#pragma unroll
            for (int j = 0; j < 4; ++j) { v[j] = f2bf(a[j]); v[4 + j] = f2bf(b[j]); }
        } else {
            v = ((const short8*)xin)[i];
        }
        ((short8*)xb)[i] = v;
    }
}

// ---------------- kernel 0: W [16][1024][64] -> Wt [16][64][1024] (bf16) ----------------
__global__ __launch_bounds__(256) void transpose_w(const void* __restrict__ W0,
                                                   const void* __restrict__ W1,
                                                   const void* __restrict__ W2,
                                                   const int* __restrict__ flag,
                                                   short* __restrict__ Wt) {
    __shared__ short tile[64][72];
    const bool isf = (flag[0] != 0);
    const int s  = blockIdx.z;
    const void* W = (s == 0) ? W0 : (s == 1) ? W1 : W2;
    const int h  = blockIdx.y;
    const int c0 = blockIdx.x * 64;
    const int t  = threadIdx.x;
#pragma unroll
    for (int p = 0; p < 2; ++p) {
        int f8 = t + p * 256;
        int r  = f8 >> 3;
        int c8 = (f8 & 7) * 8;
        size_t base = (size_t)(h * 1024 + c0 + r) * 64 + c8;
        short8 v;
        if (isf) {
            const float* wf = (const float*)W + base;
#pragma unroll
            for (int j = 0; j < 8; ++j) v[j] = f2bf(wf[j]);
        } else {
            v = *(const short8*)((const short*)W + base);
        }
        *(short8*)&tile[r][c8] = v;
    }
    __syncthreads();
#pragma unroll
    for (int p = 0; p < 2; ++p) {
        int f8 = t + p * 256;
        int d  = f8 >> 3;
        int c8 = (f8 & 7) * 8;
        short8 v;
#pragma unroll
        for (int j = 0; j < 8; ++j) v[j] = tile[c8 + j][d];
        *(short8*)(Wt + (size_t)((s * 16 + h) * 64 + d) * 1024 + c0 + c8) = v;
    }
}

// ---------------- kernel 1: QKV projection as one 128x128-tile GEMM ----------------
// A = xb [8192][1024], B = Wt [3072][1024] (B^T layout), C scattered into qkv.
// grid (64, 24), block 256 (4 waves, 2x2). BK=32, global_load_lds width 16,
// both-sides swizzle: 16B slot ^= (row>>1)&3 on global src AND on ds_read.
__global__ __launch_bounds__(256) void qkv_gemm(const short* __restrict__ xb,
                                                const short* __restrict__ Wt,
                                                short* __restrict__ qkv) {
    __shared__ short As[128 * 32];
    __shared__ short Bs[128 * 32];
    const int m0 = blockIdx.x * 128;
    const int n0 = blockIdx.y * 128;
    const int tid = threadIdx.x;
    const int wv = tid >> 6, ln = tid & 63;
    const int lr = ln & 15, lg = ln >> 4;
    const int wr = wv >> 1, wc = wv & 1;
    const int s = n0 >> 10;                  // 0=q 1=k 2=v (uniform per block)
    const int b = m0 >> 11;                  // batch (uniform per block)
    const float qs = (s == 0) ? 0.18033688f : 1.0f;   // 0.125 * log2(e)

    // staging: lane ln -> row ln>>2 within chunk, swizzled 16B slot
    const int srow = ln >> 2;
    const int sgrp = ((ln & 3) ^ ((ln >> 3) & 3)) * 8;     // slot ^ (row>>1)&3
    // fragment ds_read slot (same involution)
    const int roff = (lg ^ ((lr >> 1) & 3)) * 8;

    f32x4 acc[4][4] = {};
    const short* Abase = xb + (size_t)m0 * 1024;
    const short* Bbase = Wt + (size_t)n0 * 1024;

    for (int k0 = 0; k0 < 1024; k0 += 32) {
        // each wave stages rows [wv*16,+16) and [64+wv*16,+16) of A and B
        const int r0 = wv * 16, r1 = 64 + wv * 16;
        GLOAD16(Abase + (size_t)(r0 + srow) * 1024 + k0 + sgrp, As + r0 * 32);
        GLOAD16(Abase + (size_t)(r1 + srow) * 1024 + k0 + sgrp, As + r1 * 32);
        GLOAD16(Bbase + (size_t)(r0 + srow) * 1024 + k0 + sgrp, Bs + r0 * 32);
        GLOAD16(Bbase + (size_t)(r1 + srow) * 1024 + k0 + sgrp, Bs + r1 * 32);
        __syncthreads();                     // vmcnt(0) drained by barrier
        short8 af[4], bfr[4];
#pragma unroll
        for (int i = 0; i < 4; ++i)
            af[i] = *(const short8*)&As[(wr * 64 + i * 16 + lr) * 32 + roff];
#pragma unroll
        for (int i = 0; i < 4; ++i)
            bfr[i] = *(const short8*)&Bs[(wc * 64 + i * 16 + lr) * 32 + roff];
#pragma unroll
        for (int mi = 0; mi < 4; ++mi)
#pragma unroll
            for (int ni = 0; ni < 4; ++ni)
                acc[mi][ni] = __builtin_amdgcn_mfma_f32_16x16x32_bf16(af[mi], bfr[ni], acc[mi][ni], 0, 0, 0);
        __syncthreads();
    }

    // epilogue: scatter into qkv[s][b][h][t][d]
#pragma unroll
    for (int ni = 0; ni < 4; ++ni) {
        const int colbase = n0 + wc * 64 + ni * 16;       // + lr
        const int h  = (colbase >> 6) & 15;
        const int d0 = colbase & 63;
        short* orow = qkv + (size_t)((s * 4 + b) * 16 + h) * 2048 * 64 + d0 + lr;
#pragma unroll
        for (int mi = 0; mi < 4; ++mi)
#pragma unroll
            for (int r = 0; r < 4; ++r) {
                int t = (m0 & 2047) + wr * 64 + mi * 16 + lg * 4 + r;
                orow[(size_t)t * 64] = f2bf(acc[mi][ni][r] * qs);
            }
    }
}

// ---------------- kernel 2: balanced causal flash attention ----------------
// grid (8,16,4): block qbl handles q-tiles {qbl, 15-qbl} (equal work). One KV
// sweep serves both. Double-buffered LDS. Swapped 32x32 MFMA, in-register
// softmax, defer-max, lane-local lsum.
#define BUILD_PW(s, stx, base) {                                             \
    unsigned P01 = cvtpk_bf16(stx[base + 0], stx[base + 1]);                 \
    unsigned P23 = cvtpk_bf16(stx[base + 2], stx[base + 3]);                 \
    unsigned P45 = cvtpk_bf16(stx[base + 4], stx[base + 5]);                 \
    unsigned P67 = cvtpk_bf16(stx[base + 6], stx[base + 7]);                 \
    unsigned Q01 = (unsigned)__shfl_xor((int)P01, 32);                       \
    unsigned Q23 = (unsigned)__shfl_xor((int)P23, 32);                       \
    unsigned Q45 = (unsigned)__shfl_xor((int)P45, 32);                       \
    unsigned Q67 = (unsigned)__shfl_xor((int)P67, 32);                       \
    pw[s][0] = hl ? Q45 : P01;  pw[s][1] = hl ? Q67 : P23;                   \
    pw[s][2] = hl ? P45 : Q01;  pw[s][3] = hl ? P67 : Q23;                   \
}

__device__ __forceinline__ void process_tile(const char* KsB, const char* VtB,
                                             short8 a0, short8 a1, short8 a2, short8 a3,
                                             float& mr, float& ls,
                                             f32x16& o0, f32x16& o1,
                                             int qg, int kv0, bool diag,
                                             int q_, int hl) {
    short8 aq[4] = {a0, a1, a2, a3};
    f32x16 st0 = {}, st1 = {};
#pragma unroll
    for (int s = 0; s < 4; ++s) {
        short8 kf0 = *(const short8*)(KsB + swz(q_,      s * 32 + hl * 16));
        short8 kf1 = *(const short8*)(KsB + swz(32 + q_, s * 32 + hl * 16));
        st0 = __builtin_amdgcn_mfma_f32_32x32x16_bf16(kf0, aq[s], st0, 0, 0, 0);
        st1 = __builtin_amdgcn_mfma_f32_32x32x16_bf16(kf1, aq[s], st1, 0, 0, 0);
    }
    if (diag) {
#pragma unroll
        for (int r = 0; r < 16; ++r) {
            int key = kv0 + (r & 3) + 8 * (r >> 2) + 4 * hl;
            st0[r] = (key      <= qg) ? st0[r] : -1.0e30f;
            st1[r] = (key + 32 <= qg) ? st1[r] : -1.0e30f;
        }
    }
    float mx = fmaxf(st0[0], st1[0]);
#pragma unroll
    for (int r = 1; r < 16; ++r) mx = fmaxf(mx, fmaxf(st0[r], st1[r]));
    mx = fmaxf(mx, __shfl_xor(mx, 32));
    if (!__all(mx <= mr + 8.0f)) {        // defer-max
        float mnew  = fmaxf(mr, mx);
        float alpha = exp2f(mr - mnew);
        ls *= alpha;
#pragma unroll
        for (int r = 0; r < 16; ++r) { o0[r] *= alpha; o1[r] *= alpha; }
        mr = mnew;
    }
    float rs = 0.f;
#pragma unroll
    for (int r = 0; r < 16; ++r) {
        st0[r] = exp2f(st0[r] - mr); rs += st0[r];
        st1[r] = exp2f(st1[r] - mr); rs += st1[r];
    }
    ls += rs;                              // lane-local; partner half added at end
    unsigned pw[4][4];
    BUILD_PW(0, st0, 0)
    BUILD_PW(1, st0, 8)
    BUILD_PW(2, st1, 0)
    BUILD_PW(3, st1, 8)
#pragma unroll
    for (int s = 0; s < 4; ++s) {
        union { unsigned u[4]; short8 s8; } pb;
        pb.u[0] = pw[s][0]; pb.u[1] = pw[s][1]; pb.u[2] = pw[s][2]; pb.u[3] = pw[s][3];
        short8 v0 = *(const short8*)(VtB + swz(q_,      s * 32 + hl * 16));
        short8 v1 = *(const short8*)(VtB + swz(32 + q_, s * 32 + hl * 16));
        o0 = __builtin_amdgcn_mfma_f32_32x32x16_bf16(v0, pb.s8, o0, 0, 0, 0);
        o1 = __builtin_amdgcn_mfma_f32_32x32x16_bf16(v1, pb.s8, o1, 0, 0, 0);
    }
}

#define EPILOGUE(oA, oB, lsv, q0base) {                                           \
    __syncthreads();                                                              \
    float inv = 1.0f / (lsv);                                                     \
    const int qlocal = w * 32 + q_;                                               \
    _Pragma("unroll")                                                             \
    for (int r = 0; r < 16; r += 2) {                                             \
        int d0 = (r & 3) + 8 * (r >> 2) + 4 * hl;                                 \
        *(unsigned*)(OtB + swz(qlocal, 2 * d0)) =                                 \
            cvtpk_bf16(oA[r] * inv, oA[r + 1] * inv);                             \
        *(unsigned*)(OtB + swz(qlocal, 2 * (32 + d0))) =                          \
            cvtpk_bf16(oB[r] * inv, oB[r + 1] * inv);                             \
    }                                                                             \
    __syncthreads();                                                              \
    _Pragma("unroll")                                                             \
    for (int i2 = 0; i2 < 4; ++i2) {                                              \
        int idx = i2 * 256 + tid;                                                 \
        int row = idx >> 3, cc8 = (idx & 7) * 8;                                  \
        short8 vch = *(const short8*)(OtB + swz(row, cc8 * 2));                   \
        size_t obase = (size_t)(b * 2048 + (q0base) + row) * 1024 + h * 64 + cc8; \
        if (isf) {                                                                \
            f32x4 lo2, hi2;                                                       \
            _Pragma("unroll")                                                     \
            for (int j = 0; j < 4; ++j) { lo2[j] = bf2f(vch[j]); hi2[j] = bf2f(vch[4 + j]); } \
            *(f32x4*)((float*)outp + obase)     = lo2;                            \
            *(f32x4*)((float*)outp + obase + 4) = hi2;                            \
        } else {                                                                  \
            *(short8*)((short*)outp + obase) = vch;                               \
        }                                                                         \
    }                                                                             \
}

__global__ __launch_bounds__(256, 2) void attn(const short* __restrict__ qkv,
                                               const int* __restrict__ flag,
                                               void* __restrict__ outp) {
    __shared__ short lds_all[2 * 9216];    // dbuf {Ks[64*72], Vt[64*72]} = 36 KB
    const bool isf = (flag[0] != 0);
    const int h  = blockIdx.y;
    const int b  = blockIdx.z;
    const int tid = threadIdx.x;
    const int w  = tid >> 6, l = tid & 63;
    const int q_ = l & 31;
    const int hl = l >> 5;
    const size_t BHTD = (size_t)4 * 16 * 2048 * 64;
    const short* Qb = qkv + (size_t)(b * 16 + h) * 2048 * 64;
    const short* Kb = Qb + BHTD;
    const short* Vb = Qb + 2 * BHTD;

    const int qbs0 = blockIdx.x, qbs1 = 15 - qbs0;      // paired q-tiles
    const int nt0 = 2 * qbs0 + 2, nt1 = 2 * qbs1 + 2;   // nt0 <= nt1
    const int qg0 = qbs0 * 128 + w * 32 + q_;
    const int qg1 = qbs1 * 128 + w * 32 + q_;

    short8 aq0[4], aq1[4];
#pragma unroll
    for (int s = 0; s < 4; ++s) {
        aq0[s] = *(const short8*)(Qb + (size_t)qg0 * 64 + s * 16 + hl * 8);
        aq1[s] = *(const short8*)(Qb + (size_t)qg1 * 64 + s * 16 + hl * 8);
    }

    float mr0 = -1.0e30f, ls0 = 0.f, mr1 = -1.0e30f, ls1 = 0.f;
    f32x16 o00 = {}, o01 = {}, o10 = {}, o11 = {};

    const int kr = (tid >> 3) * 2;       // 2 adjacent key rows per thread
    const int c8 = (tid & 7) * 8;
    short8 kreg[2], vreg[2];

    {   // prologue: stage tile 0 into buf 0
        kreg[0] = *(const short8*)(Kb + (size_t)kr * 64 + c8);
        kreg[1] = *(const short8*)(Kb + (size_t)(kr + 1) * 64 + c8);
        vreg[0] = *(const short8*)(Vb + (size_t)kr * 64 + c8);
        vreg[1] = *(const short8*)(Vb + (size_t)(kr + 1) * 64 + c8);
        char* KsN = (char*)lds_all;
        char* VtN = KsN + 9216;
        *(short8*)(KsN + swz(kr,     c8 * 2)) = kreg[0];
        *(short8*)(KsN + swz(kr + 1, c8 * 2)) = kreg[1];
#pragma unroll
        for (int j = 0; j < 8; ++j) {
            unsigned pv = (unsigned)(unsigned short)vreg[0][j]
                        | ((unsigned)(unsigned short)vreg[1][j] << 16);
            *(unsigned*)(VtN + swz(c8 + j, kr * 2)) = pv;
        }
    }

    for (int kt = 0; kt < nt1; ++kt) {
        const char* KsB = (const char*)lds_all + (kt & 1) * 18432;
        const char* VtB = KsB + 9216;
        __syncthreads();                   // staged writes visible; prev readers done
        if (kt + 1 < nt1) {                // issue next tile's loads early
            const short* Kn = Kb + (size_t)(kt + 1) * 4096;
            const short* Vn = Vb + (size_t)(kt + 1) * 4096;
            kreg[0] = *(const short8*)(Kn + (size_t)kr * 64 + c8);
            kreg[1] = *(const short8*)(Kn + (size_t)(kr + 1) * 64 + c8);
            vreg[0] = *(const short8*)(Vn + (size_t)kr * 64 + c8);
            vreg[1] = *(const short8*)(Vn + (size_t)(kr + 1) * 64 + c8);
        }
        const int kv0 = kt * 64;
        process_tile(KsB, VtB, aq1[0], aq1[1], aq1[2], aq1[3], mr1, ls1,
                     o10, o11, qg1, kv0, kt >= 2 * qbs1, q_, hl);
        if (kt < nt0)
            process_tile(KsB, VtB, aq0[0], aq0[1], aq0[2], aq0[3], mr0, ls0,
                         o00, o01, qg0, kv0, kt >= 2 * qbs0, q_, hl);
        if (kt + 1 < nt1) {                // write next tile into other buffer
            char* KsN = (char*)lds_all + ((kt + 1) & 1) * 18432;
            char* VtN = KsN + 9216;
            *(short8*)(KsN + swz(kr,     c8 * 2)) = kreg[0];
            *(short8*)(KsN + swz(kr + 1, c8 * 2)) = kreg[1];
#pragma unroll
            for (int j = 0; j < 8; ++j) {
                unsigned pv = (unsigned)(unsigned short)vreg[0][j]
                            | ((unsigned)(unsigned short)vreg[1][j] << 16);
                *(unsigned*)(VtN + swz(c8 + j, kr * 2)) = pv;
            }
        }
    }

    ls0 += __shfl_xor(ls0, 32);
    ls1 += __shfl_xor(ls1, 32);
    char* const OtB = (char*)lds_all;      // epilogue reuses buffer 0 (128x72)
    EPILOGUE(o00, o01, ls0, qbs0 * 128)
    EPILOGUE(o10, o11, ls1, qbs1 * 128)
}

extern "C" void kernel_launch(void* const* d_in, const int* in_sizes, int n_in,
                              void* d_out, int out_size, void* d_ws, size_t ws_size,
                              hipStream_t stream) {
    short* ws   = (short*)d_ws;
    int*  flag  = (int*)d_ws;
    short* xb   = ws + XB_OFF;
    short* Wt   = ws + WT_OFF;
    short* qkvb = ws + QKV_OFF;

    dim3 blk(256);
    detect_dtype<<<1, blk, 0, stream>>>((const unsigned short*)d_in[0], flag);
    convert_x<<<dim3(1024), blk, 0, stream>>>(d_in[0], flag, xb);
    transpose_w<<<dim3(16, 16, 3), blk, 0, stream>>>(d_in[1], d_in[2], d_in[3], flag, Wt);
    qkv_gemm<<<dim3(64, 24), blk, 0, stream>>>(xb, Wt, qkvb);
    attn<<<dim3(8, 16, 4), blk, 0, stream>>>(qkvb, flag, d_out);
}